// Round 2
// baseline (1781.967 us; speedup 1.0000x reference)
//
#include <hip/hip_runtime.h>

// Problem constants (B=1 fixed)
#define CC   32
#define DD   24
#define HH   96
#define WW   96
#define HWC  (HH*WW)        // 9216
#define DHW  (DD*HH*WW)     // 221184
#define NG   4
#define CPG  (CC/NG)        // 8
#define OC1  54
#define GN_EPS 1e-5f

// ---------------- weight transpose: src[o][c][tap] -> dst[(tap*32+c)*O + o] ----------------
__global__ void transpose_w(const float* __restrict__ src, float* __restrict__ dst,
                            int O, int n) {
    int idx = blockIdx.x * 256 + threadIdx.x;
    if (idx >= n) return;
    int o    = idx % O;
    int rest = idx / O;
    int c    = rest % CC;
    int tap  = rest / CC;
    dst[idx] = src[(o * CC + c) * 27 + tap];
}

// ---------------- group-norm stats: sum & sumsq per group ----------------
__global__ void gn_stats(const float* __restrict__ x, float* __restrict__ stats) {
    // grid = NG*32 blocks, 256 threads
    const int g = blockIdx.x >> 5;
    const int s = blockIdx.x & 31;
    const float4* base = (const float4*)(x + (size_t)g * CPG * DHW);
    const int n4 = CPG * DHW / 4;  // 442368
    float s1 = 0.f, s2 = 0.f;
    for (int idx = s * 256 + threadIdx.x; idx < n4; idx += 32 * 256) {
        float4 v = base[idx];
        s1 += v.x + v.y + v.z + v.w;
        s2 += v.x * v.x + v.y * v.y + v.z * v.z + v.w * v.w;
    }
    for (int off = 32; off > 0; off >>= 1) {
        s1 += __shfl_down(s1, off);
        s2 += __shfl_down(s2, off);
    }
    __shared__ float ls1[4], ls2[4];
    int wid = threadIdx.x >> 6;
    if ((threadIdx.x & 63) == 0) { ls1[wid] = s1; ls2[wid] = s2; }
    __syncthreads();
    if (threadIdx.x == 0) {
        float a = 0.f, b = 0.f;
        for (int i = 0; i < 4; i++) { a += ls1[i]; b += ls2[i]; }
        atomicAdd(&stats[g * 2 + 0], a);
        atomicAdd(&stats[g * 2 + 1], b);
    }
}

// ---------------- group-norm apply + relu + transpose to channels-last ----------------
// in:  x[C][DHW]   out: yT[DHW][C]
__global__ void gn_apply_T(const float* __restrict__ x, const float* __restrict__ stats,
                           const float* __restrict__ gamma, const float* __restrict__ beta,
                           float* __restrict__ yT) {
    const int p = blockIdx.x * 256 + threadIdx.x;
    const float invN = 1.0f / (float)(CPG * DHW);
    float mean[NG], rstd[NG];
#pragma unroll
    for (int g = 0; g < NG; g++) {
        mean[g] = stats[2 * g] * invN;
        float var = stats[2 * g + 1] * invN - mean[g] * mean[g];
        rstd[g] = rsqrtf(var + GN_EPS);
    }
    float vals[CC];
#pragma unroll
    for (int c = 0; c < CC; c++) {
        const int g = c >> 3;
        const float ga = gamma[c] * rstd[g];
        const float be = beta[c] - mean[g] * ga;
        vals[c] = fmaxf(0.f, x[(size_t)c * DHW + p] * ga + be);
    }
    float* dst = yT + (size_t)p * CC;
#pragma unroll
    for (int q = 0; q < 8; q++) {
        float4 v = make_float4(vals[q * 4 + 0], vals[q * 4 + 1], vals[q * 4 + 2], vals[q * 4 + 3]);
        ((float4*)dst)[q] = v;
    }
}

// ---------------- dense 3x3x3 conv, 32 -> 54 ch, pad 1; channels-last input ----------------
// xT: [D][H][W][32], wT: [(tap*32+c)*54 + o], out: [54][DHW]
__global__ __launch_bounds__(192) void offs_conv(const float* __restrict__ xT,
                                                 const float* __restrict__ wT,
                                                 const float* __restrict__ bias,
                                                 float* __restrict__ outp) {
    const int t = threadIdx.x;
    const int r = blockIdx.x * 2 + (t / 96);   // row index in [0, D*H)
    const int w = t % 96;
    const int d = r / HH;
    const int h = r % HH;
    const int p = r * WW + w;

    float acc[OC1];
#pragma unroll
    for (int o = 0; o < OC1; o++) acc[o] = 0.f;

#pragma unroll 1
    for (int i = 0; i < 3; i++) {
        const int dd = d + i - 1;
        if (dd < 0 || dd >= DD) continue;
#pragma unroll 1
        for (int j = 0; j < 3; j++) {
            const int hh2 = h + j - 1;
            if (hh2 < 0 || hh2 >= HH) continue;
            const float* rowb = xT + ((size_t)(dd * HH + hh2) * WW) * CC;
#pragma unroll 1
            for (int k = 0; k < 3; k++) {
                const int ww2 = w + k - 1;
                if (ww2 < 0 || ww2 >= WW) continue;
                const float* px = rowb + ww2 * CC;
                const float* wp = wT + (size_t)((i * 9 + j * 3 + k) * CC) * OC1;
#pragma unroll
                for (int q = 0; q < 8; q++) {
                    const float4 v = *(const float4*)(px + q * 4);
                    const float* wq = wp + q * 4 * OC1;
#pragma unroll
                    for (int o = 0; o < OC1; o++) acc[o] = fmaf(v.x, wq[o], acc[o]);
#pragma unroll
                    for (int o = 0; o < OC1; o++) acc[o] = fmaf(v.y, wq[OC1 + o], acc[o]);
#pragma unroll
                    for (int o = 0; o < OC1; o++) acc[o] = fmaf(v.z, wq[2 * OC1 + o], acc[o]);
#pragma unroll
                    for (int o = 0; o < OC1; o++) acc[o] = fmaf(v.w, wq[3 * OC1 + o], acc[o]);
                }
            }
        }
    }
#pragma unroll
    for (int o = 0; o < OC1; o++) outp[(size_t)o * DHW + p] = acc[o] + bias[o];
}

// ---------------- deformable conv (H/W bilinear, D shift, zero pad); channels-last x ----------------
// xT: [D][H][W][32], wT: [(tap*32+c)*32 + o], off: [54][DHW], out: [32][DHW]
__global__ __launch_bounds__(192) void deform_conv(const float* __restrict__ xT,
                                                   const float* __restrict__ off,
                                                   const float* __restrict__ wT,
                                                   const float* __restrict__ bias,
                                                   const float* __restrict__ resid,
                                                   float* __restrict__ outp) {
    const int t = threadIdx.x;
    const int r = blockIdx.x * 2 + (t / 96);
    const int w = t % 96;
    const int d = r / HH;
    const int h = r % HH;
    const int p = r * WW + w;

    float acc[CC];
#pragma unroll
    for (int o = 0; o < CC; o++) acc[o] = 0.f;

#pragma unroll 1
    for (int i = 0; i < 3; i++) {
        const int dd = d + i - 1;
        if (dd < 0 || dd >= DD) continue;   // zero-padded depth
        const float* xd = xT + (size_t)dd * HWC * CC;
#pragma unroll 1
        for (int jk = 0; jk < 9; jk++) {
            const int j = jk / 3;
            const int k = jk % 3;
            const int tap = i * 9 + jk;
            const float oh  = off[(size_t)(tap * 2 + 0) * DHW + p];
            const float owv = off[(size_t)(tap * 2 + 1) * DHW + p];
            const float hp  = (float)(h + j - 1) + oh;
            const float wpf = (float)(w + k - 1) + owv;
            const float h0f = floorf(hp), w0f = floorf(wpf);
            const int h0 = (int)h0f, w0 = (int)w0f;
            const float lh = hp - h0f, lw = wpf - w0f;
            const bool hv0 = (h0 >= 0) && (h0 < HH);
            const bool hv1 = (h0 >= -1) && (h0 < HH - 1);
            const bool wv0 = (w0 >= 0) && (w0 < WW);
            const bool wv1 = (w0 >= -1) && (w0 < WW - 1);
            const float c00 = (hv0 && wv0) ? (1.f - lh) * (1.f - lw) : 0.f;
            const float c01 = (hv0 && wv1) ? (1.f - lh) * lw : 0.f;
            const float c10 = (hv1 && wv0) ? lh * (1.f - lw) : 0.f;
            const float c11 = (hv1 && wv1) ? lh * lw : 0.f;
            const int h0c = min(max(h0, 0), HH - 1);
            const int h1c = min(max(h0 + 1, 0), HH - 1);
            const int w0c = min(max(w0, 0), WW - 1);
            const int w1c = min(max(w0 + 1, 0), WW - 1);
            const float* g00 = xd + (size_t)(h0c * WW + w0c) * CC;
            const float* g01 = xd + (size_t)(h0c * WW + w1c) * CC;
            const float* g10 = xd + (size_t)(h1c * WW + w0c) * CC;
            const float* g11 = xd + (size_t)(h1c * WW + w1c) * CC;
            const float* wp = wT + (size_t)(tap * CC) * CC;
#pragma unroll
            for (int q = 0; q < 8; q++) {
                const float4 a = *(const float4*)(g00 + q * 4);
                const float4 b = *(const float4*)(g01 + q * 4);
                const float4 cg = *(const float4*)(g10 + q * 4);
                const float4 dg = *(const float4*)(g11 + q * 4);
                const float v0 = c00 * a.x + c01 * b.x + c10 * cg.x + c11 * dg.x;
                const float v1 = c00 * a.y + c01 * b.y + c10 * cg.y + c11 * dg.y;
                const float v2 = c00 * a.z + c01 * b.z + c10 * cg.z + c11 * dg.z;
                const float v3 = c00 * a.w + c01 * b.w + c10 * cg.w + c11 * dg.w;
                const float* wq = wp + q * 4 * CC;
#pragma unroll
                for (int o = 0; o < CC; o++) acc[o] = fmaf(v0, wq[o], acc[o]);
#pragma unroll
                for (int o = 0; o < CC; o++) acc[o] = fmaf(v1, wq[CC + o], acc[o]);
#pragma unroll
                for (int o = 0; o < CC; o++) acc[o] = fmaf(v2, wq[2 * CC + o], acc[o]);
#pragma unroll
                for (int o = 0; o < CC; o++) acc[o] = fmaf(v3, wq[3 * CC + o], acc[o]);
            }
        }
    }
    if (resid) {
#pragma unroll
        for (int o = 0; o < CC; o++)
            outp[(size_t)o * DHW + p] = acc[o] + bias[o] + resid[(size_t)o * DHW + p];
    } else {
#pragma unroll
        for (int o = 0; o < CC; o++)
            outp[(size_t)o * DHW + p] = acc[o] + bias[o];
    }
}

extern "C" void kernel_launch(void* const* d_in, const int* in_sizes, int n_in,
                              void* d_out, int out_size, void* d_ws, size_t ws_size,
                              hipStream_t stream) {
    const float* x   = (const float*)d_in[0];
    const float* g1  = (const float*)d_in[1];
    const float* be1 = (const float*)d_in[2];
    const float* g2  = (const float*)d_in[3];
    const float* be2 = (const float*)d_in[4];
    const float* ow1 = (const float*)d_in[5];
    const float* ob1 = (const float*)d_in[6];
    const float* dw1 = (const float*)d_in[7];
    const float* db1 = (const float*)d_in[8];
    const float* ow2 = (const float*)d_in[9];
    const float* ob2 = (const float*)d_in[10];
    const float* dw2 = (const float*)d_in[11];
    const float* db2 = (const float*)d_in[12];
    float* out = (float*)d_out;
    float* ws  = (float*)d_ws;

    // ws layout (in floats)
    float* stats = ws;                 // 16 (zeroed each call)
    float* wT1   = ws + 256;           // 46656
    float* dwT1  = ws + 47104;         // 27648
    float* wT2   = ws + 74752;         // 46656
    float* dwT2  = ws + 121600;        // 27648
    float* h1T   = ws + 149504;        // 7077888 (channels-last, reused block 2)
    float* off1  = ws + 7227392;       // 11943936 (reused block 2)
    // deform1 output -> d_out (scratch, overwritten by deform2)

    hipMemsetAsync(stats, 0, 16 * sizeof(float), stream);
    transpose_w<<<(54 * 32 * 27 + 255) / 256, 256, 0, stream>>>(ow1, wT1, 54, 54 * 32 * 27);
    transpose_w<<<(32 * 32 * 27 + 255) / 256, 256, 0, stream>>>(dw1, dwT1, 32, 32 * 32 * 27);
    transpose_w<<<(54 * 32 * 27 + 255) / 256, 256, 0, stream>>>(ow2, wT2, 54, 54 * 32 * 27);
    transpose_w<<<(32 * 32 * 27 + 255) / 256, 256, 0, stream>>>(dw2, dwT2, 32, 32 * 32 * 27);

    // block 1
    gn_stats<<<NG * 32, 256, 0, stream>>>(x, stats + 0);
    gn_apply_T<<<DHW / 256, 256, 0, stream>>>(x, stats + 0, g1, be1, h1T);
    offs_conv<<<DD * HH / 2, 192, 0, stream>>>(h1T, wT1, ob1, off1);
    deform_conv<<<DD * HH / 2, 192, 0, stream>>>(h1T, off1, dwT1, db1, nullptr, out);

    // block 2 (input = deform1 output currently living in d_out)
    gn_stats<<<NG * 32, 256, 0, stream>>>(out, stats + 8);
    gn_apply_T<<<DHW / 256, 256, 0, stream>>>(out, stats + 8, g2, be2, h1T);
    offs_conv<<<DD * HH / 2, 192, 0, stream>>>(h1T, wT2, ob2, off1);
    deform_conv<<<DD * HH / 2, 192, 0, stream>>>(h1T, off1, dwT2, db2, x, out);
}

// Round 4
// 1617.977 us; speedup vs baseline: 1.1014x; 1.1014x over previous
//
#include <hip/hip_runtime.h>

// Problem constants (B=1 fixed)
#define CC   32
#define DD   24
#define HH   96
#define WW   96
#define HWC  (HH*WW)        // 9216
#define DHW  (DD*HH*WW)     // 221184
#define NG   4
#define CPG  (CC/NG)        // 8
#define OC1  54
#define GN_EPS 1e-5f
#define NBLK (DD*HH/2)      // 1152
#define CHUNK (NBLK/8)      // 144

typedef float f32x4 __attribute__((ext_vector_type(4)));

// XCD-chunked swizzle: hardware assigns block b -> XCD b%8; give each XCD a
// contiguous chunk of row-pairs so its 4MB L2 holds the stencil working set.
__device__ __forceinline__ int swz_block(int bid) {
    return (bid % 8) * CHUNK + (bid / 8);
}

// ---------------- weight transpose: src[o][c][tap] -> dst[(tap*32+c)*O + o] ----------------
__global__ void transpose_w(const float* __restrict__ src, float* __restrict__ dst,
                            int O, int n) {
    int idx = blockIdx.x * 256 + threadIdx.x;
    if (idx >= n) return;
    int o    = idx % O;
    int rest = idx / O;
    int c    = rest % CC;
    int tap  = rest / CC;
    dst[idx] = src[(o * CC + c) * 27 + tap];
}

// ---------------- group-norm stats: sum & sumsq per group ----------------
__global__ void gn_stats(const float* __restrict__ x, float* __restrict__ stats) {
    const int g = blockIdx.x >> 5;
    const int s = blockIdx.x & 31;
    const float4* base = (const float4*)(x + (size_t)g * CPG * DHW);
    const int n4 = CPG * DHW / 4;
    float s1 = 0.f, s2 = 0.f;
    for (int idx = s * 256 + threadIdx.x; idx < n4; idx += 32 * 256) {
        float4 v = base[idx];
        s1 += v.x + v.y + v.z + v.w;
        s2 += v.x * v.x + v.y * v.y + v.z * v.z + v.w * v.w;
    }
    for (int off = 32; off > 0; off >>= 1) {
        s1 += __shfl_down(s1, off);
        s2 += __shfl_down(s2, off);
    }
    __shared__ float ls1[4], ls2[4];
    int wid = threadIdx.x >> 6;
    if ((threadIdx.x & 63) == 0) { ls1[wid] = s1; ls2[wid] = s2; }
    __syncthreads();
    if (threadIdx.x == 0) {
        float a = 0.f, b = 0.f;
        for (int i = 0; i < 4; i++) { a += ls1[i]; b += ls2[i]; }
        atomicAdd(&stats[g * 2 + 0], a);
        atomicAdd(&stats[g * 2 + 1], b);
    }
}

// ---------------- group-norm apply + relu + transpose to channels-last ----------------
__global__ void gn_apply_T(const float* __restrict__ x, const float* __restrict__ stats,
                           const float* __restrict__ gamma, const float* __restrict__ beta,
                           float* __restrict__ yT) {
    const int p = blockIdx.x * 256 + threadIdx.x;
    const float invN = 1.0f / (float)(CPG * DHW);
    float mean[NG], rstd[NG];
#pragma unroll
    for (int g = 0; g < NG; g++) {
        mean[g] = stats[2 * g] * invN;
        float var = stats[2 * g + 1] * invN - mean[g] * mean[g];
        rstd[g] = rsqrtf(var + GN_EPS);
    }
    float vals[CC];
#pragma unroll
    for (int c = 0; c < CC; c++) {
        const int g = c >> 3;
        const float ga = gamma[c] * rstd[g];
        const float be = beta[c] - mean[g] * ga;
        vals[c] = fmaxf(0.f, x[(size_t)c * DHW + p] * ga + be);
    }
    float* dst = yT + (size_t)p * CC;
#pragma unroll
    for (int q = 0; q < 8; q++) {
        f32x4 v = { vals[q * 4 + 0], vals[q * 4 + 1], vals[q * 4 + 2], vals[q * 4 + 3] };
        __builtin_nontemporal_store(v, (f32x4*)dst + q);
    }
}

// ---------------- dense 3x3x3 conv, 32 -> 54 ch, pad 1; channels-last input ----------------
__global__ __launch_bounds__(192) void offs_conv(const float* __restrict__ xT,
                                                 const float* __restrict__ wT,
                                                 const float* __restrict__ bias,
                                                 float* __restrict__ outp) {
    const int t = threadIdx.x;
    const int r = swz_block(blockIdx.x) * 2 + (t / 96);
    const int w = t % 96;
    const int d = r / HH;
    const int h = r % HH;
    const int p = r * WW + w;

    float acc[OC1];
#pragma unroll
    for (int o = 0; o < OC1; o++) acc[o] = 0.f;

#pragma unroll 1
    for (int i = 0; i < 3; i++) {
        const int dd = d + i - 1;
        if (dd < 0 || dd >= DD) continue;
#pragma unroll 1
        for (int j = 0; j < 3; j++) {
            const int hh2 = h + j - 1;
            if (hh2 < 0 || hh2 >= HH) continue;
            const float* rowb = xT + ((size_t)(dd * HH + hh2) * WW) * CC;
#pragma unroll 1
            for (int k = 0; k < 3; k++) {
                const int ww2 = w + k - 1;
                if (ww2 < 0 || ww2 >= WW) continue;
                const float* px = rowb + ww2 * CC;
                const float* wp = wT + (size_t)((i * 9 + j * 3 + k) * CC) * OC1;
#pragma unroll
                for (int q = 0; q < 8; q++) {
                    const float4 v = *(const float4*)(px + q * 4);
                    const float* wq = wp + q * 4 * OC1;
#pragma unroll
                    for (int o = 0; o < OC1; o++) acc[o] = fmaf(v.x, wq[o], acc[o]);
#pragma unroll
                    for (int o = 0; o < OC1; o++) acc[o] = fmaf(v.y, wq[OC1 + o], acc[o]);
#pragma unroll
                    for (int o = 0; o < OC1; o++) acc[o] = fmaf(v.z, wq[2 * OC1 + o], acc[o]);
#pragma unroll
                    for (int o = 0; o < OC1; o++) acc[o] = fmaf(v.w, wq[3 * OC1 + o], acc[o]);
                }
            }
        }
    }
#pragma unroll
    for (int o = 0; o < OC1; o++)
        __builtin_nontemporal_store(acc[o] + bias[o], outp + (size_t)o * DHW + p);
}

// ---------------- deformable conv (H/W bilinear, D shift, zero pad); channels-last x ----------------
__global__ __launch_bounds__(192) void deform_conv(const float* __restrict__ xT,
                                                   const float* __restrict__ off,
                                                   const float* __restrict__ wT,
                                                   const float* __restrict__ bias,
                                                   const float* __restrict__ resid,
                                                   float* __restrict__ outp) {
    const int t = threadIdx.x;
    const int r = swz_block(blockIdx.x) * 2 + (t / 96);
    const int w = t % 96;
    const int d = r / HH;
    const int h = r % HH;
    const int p = r * WW + w;

    float acc[CC];
#pragma unroll
    for (int o = 0; o < CC; o++) acc[o] = 0.f;

#pragma unroll 1
    for (int i = 0; i < 3; i++) {
        const int dd = d + i - 1;
        if (dd < 0 || dd >= DD) continue;   // zero-padded depth
        const float* xd = xT + (size_t)dd * HWC * CC;
#pragma unroll 1
        for (int jk = 0; jk < 9; jk++) {
            const int j = jk / 3;
            const int k = jk % 3;
            const int tap = i * 9 + jk;
            const float oh  = __builtin_nontemporal_load(off + (size_t)(tap * 2 + 0) * DHW + p);
            const float owv = __builtin_nontemporal_load(off + (size_t)(tap * 2 + 1) * DHW + p);
            const float hp  = (float)(h + j - 1) + oh;
            const float wpf = (float)(w + k - 1) + owv;
            const float h0f = floorf(hp), w0f = floorf(wpf);
            const int h0 = (int)h0f, w0 = (int)w0f;
            const float lh = hp - h0f, lw = wpf - w0f;
            const bool hv0 = (h0 >= 0) && (h0 < HH);
            const bool hv1 = (h0 >= -1) && (h0 < HH - 1);
            const bool wv0 = (w0 >= 0) && (w0 < WW);
            const bool wv1 = (w0 >= -1) && (w0 < WW - 1);
            const float c00 = (hv0 && wv0) ? (1.f - lh) * (1.f - lw) : 0.f;
            const float c01 = (hv0 && wv1) ? (1.f - lh) * lw : 0.f;
            const float c10 = (hv1 && wv0) ? lh * (1.f - lw) : 0.f;
            const float c11 = (hv1 && wv1) ? lh * lw : 0.f;
            const int h0c = min(max(h0, 0), HH - 1);
            const int h1c = min(max(h0 + 1, 0), HH - 1);
            const int w0c = min(max(w0, 0), WW - 1);
            const int w1c = min(max(w0 + 1, 0), WW - 1);
            const float* g00 = xd + (size_t)(h0c * WW + w0c) * CC;
            const float* g01 = xd + (size_t)(h0c * WW + w1c) * CC;
            const float* g10 = xd + (size_t)(h1c * WW + w0c) * CC;
            const float* g11 = xd + (size_t)(h1c * WW + w1c) * CC;
            const float* wp = wT + (size_t)(tap * CC) * CC;
#pragma unroll
            for (int q = 0; q < 8; q++) {
                const float4 a = *(const float4*)(g00 + q * 4);
                const float4 b = *(const float4*)(g01 + q * 4);
                const float4 cg = *(const float4*)(g10 + q * 4);
                const float4 dg = *(const float4*)(g11 + q * 4);
                const float v0 = c00 * a.x + c01 * b.x + c10 * cg.x + c11 * dg.x;
                const float v1 = c00 * a.y + c01 * b.y + c10 * cg.y + c11 * dg.y;
                const float v2 = c00 * a.z + c01 * b.z + c10 * cg.z + c11 * dg.z;
                const float v3 = c00 * a.w + c01 * b.w + c10 * cg.w + c11 * dg.w;
                const float* wq = wp + q * 4 * CC;
#pragma unroll
                for (int o = 0; o < CC; o++) acc[o] = fmaf(v0, wq[o], acc[o]);
#pragma unroll
                for (int o = 0; o < CC; o++) acc[o] = fmaf(v1, wq[CC + o], acc[o]);
#pragma unroll
                for (int o = 0; o < CC; o++) acc[o] = fmaf(v2, wq[2 * CC + o], acc[o]);
#pragma unroll
                for (int o = 0; o < CC; o++) acc[o] = fmaf(v3, wq[3 * CC + o], acc[o]);
            }
        }
    }
    if (resid) {
#pragma unroll
        for (int o = 0; o < CC; o++) {
            float rv = __builtin_nontemporal_load(resid + (size_t)o * DHW + p);
            __builtin_nontemporal_store(acc[o] + bias[o] + rv, outp + (size_t)o * DHW + p);
        }
    } else {
#pragma unroll
        for (int o = 0; o < CC; o++)
            __builtin_nontemporal_store(acc[o] + bias[o], outp + (size_t)o * DHW + p);
    }
}

extern "C" void kernel_launch(void* const* d_in, const int* in_sizes, int n_in,
                              void* d_out, int out_size, void* d_ws, size_t ws_size,
                              hipStream_t stream) {
    const float* x   = (const float*)d_in[0];
    const float* g1  = (const float*)d_in[1];
    const float* be1 = (const float*)d_in[2];
    const float* g2  = (const float*)d_in[3];
    const float* be2 = (const float*)d_in[4];
    const float* ow1 = (const float*)d_in[5];
    const float* ob1 = (const float*)d_in[6];
    const float* dw1 = (const float*)d_in[7];
    const float* db1 = (const float*)d_in[8];
    const float* ow2 = (const float*)d_in[9];
    const float* ob2 = (const float*)d_in[10];
    const float* dw2 = (const float*)d_in[11];
    const float* db2 = (const float*)d_in[12];
    float* out = (float*)d_out;
    float* ws  = (float*)d_ws;

    // ws layout (in floats)
    float* stats = ws;                 // 16 (zeroed each call)
    float* wT1   = ws + 256;           // 46656
    float* dwT1  = ws + 47104;         // 27648
    float* wT2   = ws + 74752;         // 46656
    float* dwT2  = ws + 121600;        // 27648
    float* h1T   = ws + 149504;        // 7077888 (channels-last, reused block 2)
    float* off1  = ws + 7227392;       // 11943936 (reused block 2)

    (void)hipMemsetAsync(stats, 0, 16 * sizeof(float), stream);
    transpose_w<<<(54 * 32 * 27 + 255) / 256, 256, 0, stream>>>(ow1, wT1, 54, 54 * 32 * 27);
    transpose_w<<<(32 * 32 * 27 + 255) / 256, 256, 0, stream>>>(dw1, dwT1, 32, 32 * 32 * 27);
    transpose_w<<<(54 * 32 * 27 + 255) / 256, 256, 0, stream>>>(ow2, wT2, 54, 54 * 32 * 27);
    transpose_w<<<(32 * 32 * 27 + 255) / 256, 256, 0, stream>>>(dw2, dwT2, 32, 32 * 32 * 27);

    // block 1
    gn_stats<<<NG * 32, 256, 0, stream>>>(x, stats + 0);
    gn_apply_T<<<DHW / 256, 256, 0, stream>>>(x, stats + 0, g1, be1, h1T);
    offs_conv<<<NBLK, 192, 0, stream>>>(h1T, wT1, ob1, off1);
    deform_conv<<<NBLK, 192, 0, stream>>>(h1T, off1, dwT1, db1, nullptr, out);

    // block 2 (input = deform1 output currently living in d_out)
    gn_stats<<<NG * 32, 256, 0, stream>>>(out, stats + 8);
    gn_apply_T<<<DHW / 256, 256, 0, stream>>>(out, stats + 8, g2, be2, h1T);
    offs_conv<<<NBLK, 192, 0, stream>>>(h1T, wT2, ob2, off1);
    deform_conv<<<NBLK, 192, 0, stream>>>(h1T, off1, dwT2, db2, x, out);
}

// Round 5
// 426.650 us; speedup vs baseline: 4.1766x; 3.7923x over previous
//
#include <hip/hip_runtime.h>
#include <hip/hip_fp16.h>

// Problem constants (B=1 fixed)
#define CC   32
#define DD   24
#define HH   96
#define WW   96
#define HWC  (HH*WW)        // 9216
#define DHW  (DD*HH*WW)     // 221184
#define NG   4
#define CPG  (CC/NG)        // 8
#define OC1  54
#define GN_EPS 1e-5f
#define NBLK2 (DHW/128)     // 1728 blocks of 128 points
#define CHUNK2 (NBLK2/8)    // 216

typedef float  f32x4 __attribute__((ext_vector_type(4)));
typedef _Float16 f16x8 __attribute__((ext_vector_type(8)));
typedef unsigned int u32x4 __attribute__((ext_vector_type(4)));

union F16Frag { f16x8 v; __half2 h2[4]; };

// XCD-chunked swizzle (1728 % 8 == 0): block b -> XCD b%8 gets contiguous chunk.
__device__ __forceinline__ int swz_block(int bid) {
    return (bid % 8) * CHUNK2 + (bid / 8);
}

// ---- pack weights into per-tap MFMA B-fragments ----
// src: [O][CC][27] fp32 (O = 54 or 32). dst: [tap][nt][lane][e] f16,
// o = nt*16 + (lane&15)  (zero-pad o >= O), c = (lane>>4)*8 + e.
__global__ void pack_w(const float* __restrict__ src, _Float16* __restrict__ dst,
                       int O, int NT, int n) {
    int idx = blockIdx.x * 256 + threadIdx.x;
    if (idx >= n) return;
    int e    = idx & 7;
    int lane = (idx >> 3) & 63;
    int nt   = (idx >> 9) % NT;
    int tap  = (idx >> 9) / NT;
    int o = nt * 16 + (lane & 15);
    int c = (lane >> 4) * 8 + e;
    float v = (o < O) ? src[(o * CC + c) * 27 + tap] : 0.f;
    dst[idx] = (_Float16)v;
}

// ---- group-norm stats ----
__global__ void gn_stats(const float* __restrict__ x, float* __restrict__ stats) {
    const int g = blockIdx.x >> 5;
    const int s = blockIdx.x & 31;
    const float4* base = (const float4*)(x + (size_t)g * CPG * DHW);
    const int n4 = CPG * DHW / 4;
    float s1 = 0.f, s2 = 0.f;
    for (int idx = s * 256 + threadIdx.x; idx < n4; idx += 32 * 256) {
        float4 v = base[idx];
        s1 += v.x + v.y + v.z + v.w;
        s2 += v.x * v.x + v.y * v.y + v.z * v.z + v.w * v.w;
    }
    for (int off = 32; off > 0; off >>= 1) {
        s1 += __shfl_down(s1, off);
        s2 += __shfl_down(s2, off);
    }
    __shared__ float ls1[4], ls2[4];
    int wid = threadIdx.x >> 6;
    if ((threadIdx.x & 63) == 0) { ls1[wid] = s1; ls2[wid] = s2; }
    __syncthreads();
    if (threadIdx.x == 0) {
        float a = 0.f, b = 0.f;
        for (int i = 0; i < 4; i++) { a += ls1[i]; b += ls2[i]; }
        atomicAdd(&stats[g * 2 + 0], a);
        atomicAdd(&stats[g * 2 + 1], b);
    }
}

// ---- group-norm apply + relu + transpose to channels-last f16 ----
__global__ void gn_apply_T(const float* __restrict__ x, const float* __restrict__ stats,
                           const float* __restrict__ gamma, const float* __restrict__ beta,
                           __half* __restrict__ yT) {
    const int p = blockIdx.x * 256 + threadIdx.x;
    const float invN = 1.0f / (float)(CPG * DHW);
    float mean[NG], rstd[NG];
#pragma unroll
    for (int g = 0; g < NG; g++) {
        mean[g] = stats[2 * g] * invN;
        float var = stats[2 * g + 1] * invN - mean[g] * mean[g];
        rstd[g] = rsqrtf(var + GN_EPS);
    }
    float vals[CC];
#pragma unroll
    for (int c = 0; c < CC; c++) {
        const int g = c >> 3;
        const float ga = gamma[c] * rstd[g];
        const float be = beta[c] - mean[g] * ga;
        vals[c] = fmaxf(0.f, x[(size_t)c * DHW + p] * ga + be);
    }
    union { __half2 h2[16]; u32x4 q[4]; } u;
#pragma unroll
    for (int c = 0; c < 16; c++) u.h2[c] = __floats2half2_rn(vals[2 * c], vals[2 * c + 1]);
    u32x4* dst = (u32x4*)(yT + (size_t)p * CC);
#pragma unroll
    for (int q = 0; q < 4; q++) __builtin_nontemporal_store(u.q[q], dst + q);
}

// ---- dense 3x3x3 conv 32->54 via MFMA; writes offsets as f16 planar [54][DHW] ----
__global__ __launch_bounds__(128) void offs_mfma(const __half* __restrict__ xT,
                                                 const _Float16* __restrict__ wB,
                                                 const float* __restrict__ bias,
                                                 __half* __restrict__ offF) {
    const int tid  = threadIdx.x;
    const int lane = tid & 63;
    const int wave = tid >> 6;
    const int p0   = swz_block(blockIdx.x) * 128;
    const int pw   = p0 + wave * 64;
    const int d    = pw / HWC;
    const int rem  = pw % HWC;
    const int mrow = lane & 15;
    const int kg   = lane >> 4;

    int hq[4], wq[4];
#pragma unroll
    for (int m = 0; m < 4; m++) {
        int rr = rem + m * 16 + mrow;
        hq[m] = rr / WW; wq[m] = rr % WW;
    }

    f32x4 acc[4][4];
#pragma unroll
    for (int m = 0; m < 4; m++)
#pragma unroll
        for (int n = 0; n < 4; n++) acc[m][n] = (f32x4){0.f, 0.f, 0.f, 0.f};

    const f16x8* wb8 = (const f16x8*)wB;

#pragma unroll 1
    for (int i = 0; i < 3; i++) {
        const int dd = d + i - 1;
        if ((unsigned)dd >= DD) continue;
        const __half* xd = xT + (size_t)dd * HWC * CC;
#pragma unroll 1
        for (int jk = 0; jk < 9; jk++) {
            const int j = jk / 3, k = jk % 3, tap = i * 9 + jk;
            const f16x8 b0 = wb8[(tap * 4 + 0) * 64 + lane];
            const f16x8 b1 = wb8[(tap * 4 + 1) * 64 + lane];
            const f16x8 b2 = wb8[(tap * 4 + 2) * 64 + lane];
            const f16x8 b3 = wb8[(tap * 4 + 3) * 64 + lane];
#pragma unroll
            for (int m = 0; m < 4; m++) {
                const int hh = hq[m] + j - 1;
                const int ww = wq[m] + k - 1;
                f16x8 a = {0, 0, 0, 0, 0, 0, 0, 0};
                if ((unsigned)hh < HH && (unsigned)ww < WW)
                    a = *(const f16x8*)(xd + (size_t)(hh * WW + ww) * CC + kg * 8);
                acc[m][0] = __builtin_amdgcn_mfma_f32_16x16x32_f16(a, b0, acc[m][0], 0, 0, 0);
                acc[m][1] = __builtin_amdgcn_mfma_f32_16x16x32_f16(a, b1, acc[m][1], 0, 0, 0);
                acc[m][2] = __builtin_amdgcn_mfma_f32_16x16x32_f16(a, b2, acc[m][2], 0, 0, 0);
                acc[m][3] = __builtin_amdgcn_mfma_f32_16x16x32_f16(a, b3, acc[m][3], 0, 0, 0);
            }
        }
    }

    __shared__ __align__(16) float lds[OC1 * 132];
#pragma unroll
    for (int m = 0; m < 4; m++)
#pragma unroll
        for (int nt = 0; nt < 4; nt++) {
            int o = nt * 16 + mrow;
            if (o < OC1)
                *(f32x4*)&lds[o * 132 + wave * 64 + m * 16 + kg * 4] = acc[m][nt];
        }
    __syncthreads();
#pragma unroll 1
    for (int o = 0; o < OC1; o++) {
        float v = lds[o * 132 + tid] + bias[o];
        offF[(size_t)o * DHW + p0 + tid] = __float2half(v);
    }
}

// ---- deformable conv via MFMA; planar fp32 output (+bias, +optional resid) ----
__global__ __launch_bounds__(128) void deform_mfma(const __half* __restrict__ xT,
                                                   const __half* __restrict__ offF,
                                                   const _Float16* __restrict__ wB,
                                                   const float* __restrict__ bias,
                                                   const float* __restrict__ resid,
                                                   float* __restrict__ outp) {
    const int tid  = threadIdx.x;
    const int lane = tid & 63;
    const int wave = tid >> 6;
    const int p0   = swz_block(blockIdx.x) * 128;
    const int pw   = p0 + wave * 64;
    const int d    = pw / HWC;
    const int rem  = pw % HWC;
    const int mrow = lane & 15;
    const int kg   = lane >> 4;

    int hq[4], wq[4];
#pragma unroll
    for (int m = 0; m < 4; m++) {
        int rr = rem + m * 16 + mrow;
        hq[m] = rr / WW; wq[m] = rr % WW;
    }

    f32x4 acc[4][2];
#pragma unroll
    for (int m = 0; m < 4; m++) {
        acc[m][0] = (f32x4){0.f, 0.f, 0.f, 0.f};
        acc[m][1] = (f32x4){0.f, 0.f, 0.f, 0.f};
    }

    const f16x8* wb8 = (const f16x8*)wB;

#pragma unroll 1
    for (int i = 0; i < 3; i++) {
        const int dd = d + i - 1;
        if ((unsigned)dd >= DD) continue;
        const __half* xd = xT + (size_t)dd * HWC * CC;
#pragma unroll 1
        for (int jk = 0; jk < 9; jk++) {
            const int j = jk / 3, k = jk % 3, tap = i * 9 + jk;
            const f16x8 b0 = wb8[(tap * 2 + 0) * 64 + lane];
            const f16x8 b1 = wb8[(tap * 2 + 1) * 64 + lane];
            const __half* offh = offF + (size_t)(tap * 2 + 0) * DHW;
            const __half* offw = offF + (size_t)(tap * 2 + 1) * DHW;
#pragma unroll
            for (int m = 0; m < 4; m++) {
                const int pq = pw + m * 16 + mrow;
                const float oh = __half2float(offh[pq]);
                const float ov = __half2float(offw[pq]);
                const float hp  = (float)(hq[m] + j - 1) + oh;
                const float wpf = (float)(wq[m] + k - 1) + ov;
                const float h0f = floorf(hp), w0f = floorf(wpf);
                const int h0 = (int)h0f, w0 = (int)w0f;
                const float lh = hp - h0f, lw = wpf - w0f;
                const bool hv0 = (h0 >= 0) && (h0 < HH);
                const bool hv1 = (h0 >= -1) && (h0 < HH - 1);
                const bool wv0 = (w0 >= 0) && (w0 < WW);
                const bool wv1 = (w0 >= -1) && (w0 < WW - 1);
                const float c00 = (hv0 && wv0) ? (1.f - lh) * (1.f - lw) : 0.f;
                const float c01 = (hv0 && wv1) ? (1.f - lh) * lw : 0.f;
                const float c10 = (hv1 && wv0) ? lh * (1.f - lw) : 0.f;
                const float c11 = (hv1 && wv1) ? lh * lw : 0.f;
                const int h0c = min(max(h0, 0), HH - 1);
                const int h1c = min(max(h0 + 1, 0), HH - 1);
                const int w0c = min(max(w0, 0), WW - 1);
                const int w1c = min(max(w0 + 1, 0), WW - 1);
                F16Frag a00, a01, a10, a11, A;
                a00.v = *(const f16x8*)(xd + (size_t)(h0c * WW + w0c) * CC + kg * 8);
                a01.v = *(const f16x8*)(xd + (size_t)(h0c * WW + w1c) * CC + kg * 8);
                a10.v = *(const f16x8*)(xd + (size_t)(h1c * WW + w0c) * CC + kg * 8);
                a11.v = *(const f16x8*)(xd + (size_t)(h1c * WW + w1c) * CC + kg * 8);
                const __half2 C00 = __float2half2_rn(c00);
                const __half2 C01 = __float2half2_rn(c01);
                const __half2 C10 = __float2half2_rn(c10);
                const __half2 C11 = __float2half2_rn(c11);
#pragma unroll
                for (int r = 0; r < 4; r++) {
                    __half2 t = __hmul2(C00, a00.h2[r]);
                    t = __hfma2(C01, a01.h2[r], t);
                    t = __hfma2(C10, a10.h2[r], t);
                    t = __hfma2(C11, a11.h2[r], t);
                    A.h2[r] = t;
                }
                acc[m][0] = __builtin_amdgcn_mfma_f32_16x16x32_f16(A.v, b0, acc[m][0], 0, 0, 0);
                acc[m][1] = __builtin_amdgcn_mfma_f32_16x16x32_f16(A.v, b1, acc[m][1], 0, 0, 0);
            }
        }
    }

    __shared__ __align__(16) float lds[CC * 132];
#pragma unroll
    for (int m = 0; m < 4; m++)
#pragma unroll
        for (int nt = 0; nt < 2; nt++) {
            int o = nt * 16 + mrow;
            *(f32x4*)&lds[o * 132 + wave * 64 + m * 16 + kg * 4] = acc[m][nt];
        }
    __syncthreads();
    if (resid) {
#pragma unroll 1
        for (int o = 0; o < CC; o++) {
            float v = lds[o * 132 + tid] + bias[o] + resid[(size_t)o * DHW + p0 + tid];
            outp[(size_t)o * DHW + p0 + tid] = v;
        }
    } else {
#pragma unroll 1
        for (int o = 0; o < CC; o++) {
            float v = lds[o * 132 + tid] + bias[o];
            outp[(size_t)o * DHW + p0 + tid] = v;
        }
    }
}

extern "C" void kernel_launch(void* const* d_in, const int* in_sizes, int n_in,
                              void* d_out, int out_size, void* d_ws, size_t ws_size,
                              hipStream_t stream) {
    const float* x   = (const float*)d_in[0];
    const float* g1  = (const float*)d_in[1];
    const float* be1 = (const float*)d_in[2];
    const float* g2  = (const float*)d_in[3];
    const float* be2 = (const float*)d_in[4];
    const float* ow1 = (const float*)d_in[5];
    const float* ob1 = (const float*)d_in[6];
    const float* dw1 = (const float*)d_in[7];
    const float* db1 = (const float*)d_in[8];
    const float* ow2 = (const float*)d_in[9];
    const float* ob2 = (const float*)d_in[10];
    const float* dw2 = (const float*)d_in[11];
    const float* db2 = (const float*)d_in[12];
    float* out = (float*)d_out;
    float* ws  = (float*)d_ws;

    // ws layout (float offsets)
    float*    stats = ws;                           // 16
    _Float16* wBo1  = (_Float16*)(ws + 256);        // 55296 h = 27648 f
    _Float16* wBd1  = (_Float16*)(ws + 27904);      // 27648 h = 13824 f
    _Float16* wBo2  = (_Float16*)(ws + 41728);      // 27648 f
    _Float16* wBd2  = (_Float16*)(ws + 69376);      // 13824 f
    __half*   hT    = (__half*)(ws + 83200);        // DHW*32 h = 3538944 f
    __half*   offF  = (__half*)(ws + 3622144);      // 54*DHW h = 5971968 f
    // total ~9.6M floats = 38.4 MB

    (void)hipMemsetAsync(stats, 0, 16 * sizeof(float), stream);
    pack_w<<<(27 * 4 * 512 + 255) / 256, 256, 0, stream>>>(ow1, wBo1, 54, 4, 27 * 4 * 512);
    pack_w<<<(27 * 2 * 512 + 255) / 256, 256, 0, stream>>>(dw1, wBd1, 32, 2, 27 * 2 * 512);
    pack_w<<<(27 * 4 * 512 + 255) / 256, 256, 0, stream>>>(ow2, wBo2, 54, 4, 27 * 4 * 512);
    pack_w<<<(27 * 2 * 512 + 255) / 256, 256, 0, stream>>>(dw2, wBd2, 32, 2, 27 * 2 * 512);

    // block 1
    gn_stats<<<NG * 32, 256, 0, stream>>>(x, stats + 0);
    gn_apply_T<<<DHW / 256, 256, 0, stream>>>(x, stats + 0, g1, be1, hT);
    offs_mfma<<<NBLK2, 128, 0, stream>>>(hT, wBo1, ob1, offF);
    deform_mfma<<<NBLK2, 128, 0, stream>>>(hT, offF, wBd1, db1, nullptr, out);

    // block 2 (input = deform1 output in d_out)
    gn_stats<<<NG * 32, 256, 0, stream>>>(out, stats + 8);
    gn_apply_T<<<DHW / 256, 256, 0, stream>>>(out, stats + 8, g2, be2, hT);
    offs_mfma<<<NBLK2, 128, 0, stream>>>(hT, wBo2, ob2, offF);
    deform_mfma<<<NBLK2, 128, 0, stream>>>(hT, offF, wBd2, db2, x, out);
}